// Round 5
// baseline (416.613 us; speedup 1.0000x reference)
//
#include <hip/hip_runtime.h>
#include <hip/hip_bf16.h>

typedef __attribute__((ext_vector_type(4))) float f32x4;
typedef __attribute__((ext_vector_type(8))) short short8;

struct bf16x4 { __hip_bfloat16 a, b, c, d; };  // 8-byte packed store unit

#define BS   8
#define SQ   2048
#define DD   256
#define KREL 64
#define NREL 129  // 2*KREL+1

// ---------------- workspace layout (bytes) ----------------
static const size_t OFF_XBF   = 0;          // bf16 [16384,256] x
static const size_t OFF_WBF   = 8388608;    // bf16 4x[256,256]: wq1/16, wk1, wq2/16, wk2
static const size_t OFF_RELBF = 8912896;    // bf16 2x[129,256]
static const size_t OFF_WR    = 9044992;    // bf16 2x[256,256] Wr = rel @ (wq/16), rows>=129 zero
static const size_t OFF_CR    = 9307136;    // f32  2x[256]     cr = rel @ (bq/16), rows>=129 zero
static const size_t OFF_QK    = 9309184;    // bf16 4x[16384,256]: Q1,K1,Q2,K2
static const size_t OFF_QR    = 42863616;   // f32  2x[16384,256]: QR1,QR2 (cols>=129 zero)

// ---------------- kernel 1: f32 -> bf16 convert (with scale fold) ----------
struct ConvArgs {
  const float* src[7];
  __hip_bfloat16* dst[7];
  float scale[7];
  int cum4[8];
};
struct bf4 { __hip_bfloat16 a, b, c, d; };

__global__ __launch_bounds__(256) void convert_k(ConvArgs A) {
  const int idx = blockIdx.x * 256 + threadIdx.x;
  if (idx >= A.cum4[7]) return;
  int rg = 0;
  #pragma unroll
  for (int t = 1; t < 7; ++t) rg += (idx >= A.cum4[t]);
  const int local = idx - A.cum4[rg];
  const float4 v = ((const float4*)A.src[rg])[local];
  const float sc = A.scale[rg];
  bf4 o;
  o.a = __float2bfloat16(v.x * sc);
  o.b = __float2bfloat16(v.y * sc);
  o.c = __float2bfloat16(v.z * sc);
  o.d = __float2bfloat16(v.w * sc);
  ((bf4*)A.dst[rg])[local] = o;  // cached: xbf is read immediately by qk_k
}

// ---------------- kernel 2: Wr[h] = rel_bf[h] @ wq_bf[h], cr[h] = rel @ bq/16
__global__ __launch_bounds__(256) void wr_k(const __hip_bfloat16* __restrict__ relbf,
                                            const __hip_bfloat16* __restrict__ wbf,
                                            const float* __restrict__ bq1,
                                            const float* __restrict__ bq2,
                                            __hip_bfloat16* __restrict__ wr,
                                            float* __restrict__ cr) {
  const int r = blockIdx.x;   // 0..255 (rows >=129 -> zero)
  const int h = blockIdx.y;   // 0..1
  const int e = threadIdx.x;  // 0..255
  const int lane = e & 63, wv = e >> 6;
  const __hip_bfloat16* rel = relbf + (size_t)h * (NREL * DD);
  const __hip_bfloat16* wq  = wbf + (size_t)h * (2 * DD * DD);  // wq1s at 0, wq2s at 131072
  float a0 = 0.f, a1 = 0.f, a2 = 0.f, a3 = 0.f;
  if (r < NREL) {
    #pragma unroll 4
    for (int d = 0; d < DD; d += 4) {
      // rel row loads are thread-uniform -> scalar; wq loads coalesced (512B/row)
      a0 += __bfloat162float(rel[r * DD + d + 0]) * __bfloat162float(wq[(d + 0) * DD + e]);
      a1 += __bfloat162float(rel[r * DD + d + 1]) * __bfloat162float(wq[(d + 1) * DD + e]);
      a2 += __bfloat162float(rel[r * DD + d + 2]) * __bfloat162float(wq[(d + 2) * DD + e]);
      a3 += __bfloat162float(rel[r * DD + d + 3]) * __bfloat162float(wq[(d + 3) * DD + e]);
    }
  }
  wr[((size_t)h * DD + r) * DD + e] = __float2bfloat16((a0 + a1) + (a2 + a3));

  // cr[h,r] = sum_e bq[e]/16 * rel[r,e]  -- parallel block reduction
  const float* bq = h ? bq2 : bq1;
  float p = (r < NREL) ? bq[e] * 0.0625f * __bfloat162float(rel[r * DD + e]) : 0.f;
  #pragma unroll
  for (int o = 32; o > 0; o >>= 1) p += __shfl_down(p, o, 64);
  __shared__ float wred[4];
  if (lane == 0) wred[wv] = p;
  __syncthreads();
  if (e == 0) cr[h * DD + r] = (wred[0] + wred[1]) + (wred[2] + wred[3]);
}

// ---------------- triple-buffered 256x128 NT-GEMM core (8 waves) -----------
// C[i,j] = sum_d A[i,d] * B[j,d]; A,B row-major bf16, ld=256, K=256.
// 512 threads = 8 waves in 4x2 (M=256, N=128); each wave does 64x64 via
// 4x4 MFMA 16x16x32 -- identical per-wave workload/epilogue to the verified
// 128x128 template; only the staging map and grid change (parameter change).
// Rationale (round-4 post-mortem): occupancy was 9 waves/CU (29%) with
// 4-wave blocks -> latency-bound. 8-wave blocks + 72KB LDS -> 2 blocks/CU
// = 16 waves/CU.
//
// LDS per buffer: A 256x32 (16KB) + B 128x32 (8KB) = 24KB; 3 buffers = 72KB.
// Staging: 1536 16B-chunks per stage / 512 lanes = 3 loads/lane.
// Chunk groups are 64-aligned, and the A/B boundary (chunk 1024) is a
// multiple of 64, so each load group is wave-uniformly A or B (no exec
// divergence around global_load_lds).
// Counted vmcnt: 3 loads/stage in a per-wave in-order FIFO -> vmcnt(3)
// retires stage k while leaving stage k+1 in flight.
__device__ __forceinline__ void stage_tile(const __hip_bfloat16* __restrict__ A,
                                           const __hip_bfloat16* __restrict__ B,
                                           int rowBase, int colBase, int k0,
                                           char* buf, int wv, int lane) {
  #pragma unroll
  for (int inst = 0; inst < 3; ++inst) {
    const int start = wv * 192 + inst * 64;            // multiple of 64
    const int lds_off = start * 16;                    // wave-uniform byte offset
    const int chunk = start + lane;                    // this lane's 16B chunk
    const __hip_bfloat16* src;
    if (start < 1024) {                                // A-region (wave-uniform test)
      const int r  = chunk >> 2;                       // 0..255
      const int kk = (chunk & 3) * 8;                  // 0,8,16,24
      src = A + (size_t)(rowBase + r) * DD + k0 + kk;
    } else {                                           // B-region
      const int c  = chunk - 1024;
      const int r  = c >> 2;                           // 0..127
      const int kk = (c & 3) * 8;
      src = B + (size_t)(colBase + r) * DD + k0 + kk;
    }
    __builtin_amdgcn_global_load_lds(
        (const __attribute__((address_space(1))) void*)src,
        (__attribute__((address_space(3))) void*)(buf + lds_off), 16, 0, 0);
  }
}

__device__ __forceinline__ void gemm_tbuf(const __hip_bfloat16* __restrict__ A,
                                          const __hip_bfloat16* __restrict__ B,
                                          int rowBase, int colBase,
                                          char* lds,  // 72 KB: 3 x (A 16KB + B 8KB)
                                          f32x4 acc[4][4]) {
  const int tid  = threadIdx.x;
  const int lane = tid & 63;
  const int wv   = tid >> 6;          // 0..7
  const int wrow = (wv >> 1) * 64;    // 0,64,128,192
  const int wcol = (wv & 1) * 64;     // 0,64
  const int m    = lane & 15;
  const int quad = lane >> 4;

  char* bufs[3] = {lds, lds + 24576, lds + 49152};

  const f32x4 zf = {0.f, 0.f, 0.f, 0.f};
  #pragma unroll
  for (int si = 0; si < 4; ++si)
    #pragma unroll
    for (int sj = 0; sj < 4; ++sj) acc[si][sj] = zf;

  // prologue: two stages in flight (6 loads/wave)
  stage_tile(A, B, rowBase, colBase, 0,  bufs[0], wv, lane);
  stage_tile(A, B, rowBase, colBase, 32, bufs[1], wv, lane);

  #pragma unroll
  for (int k = 0; k < 8; ++k) {
    // retire stage k (leave stage k+1 in flight); k=7 has nothing newer
    if (k < 7) asm volatile("s_waitcnt vmcnt(3)" ::: "memory");
    else       asm volatile("s_waitcnt vmcnt(0)" ::: "memory");
    __builtin_amdgcn_sched_barrier(0);       // pin: nothing slides into the counted window
    __builtin_amdgcn_s_barrier();            // all waves' stage k landed
    __builtin_amdgcn_sched_barrier(0);       // pin: no ds_read hoisted above barrier
    if (k < 6)
      stage_tile(A, B, rowBase, colBase, (k + 2) * 32, bufs[(k + 2) % 3], wv, lane);

    char* As = bufs[k % 3];
    char* Bs = bufs[k % 3] + 16384;
    short8 af[4], bf[4];
    #pragma unroll
    for (int s = 0; s < 4; ++s) {
      af[s] = *(const short8*)(As + (wrow + s * 16 + m) * 64 + quad * 16);
      bf[s] = *(const short8*)(Bs + (wcol + s * 16 + m) * 64 + quad * 16);
    }
    // swapped operands: D^T tile -> lane holds 4 consecutive j per acc
    #pragma unroll
    for (int si = 0; si < 4; ++si)
      #pragma unroll
      for (int sj = 0; sj < 4; ++sj)
        acc[si][sj] = __builtin_amdgcn_mfma_f32_16x16x32_bf16(bf[sj], af[si], acc[si][sj], 0, 0, 0);
  }
}

// ---------------- kernel 3: unified projection GEMM (q1,k1,qr1,q2,k2,qr2) --
struct QKArgs {
  const __hip_bfloat16* X;      // [16384,256]
  const __hip_bfloat16* W[6];   // each [256,256] (N x K, row-major)
  const float* bias[6];
  void* out[6];
  float bscale[6];
  int isf32[6];
};

__global__ __launch_bounds__(512, 4) void qk_k(QKArgs A) {
  __shared__ char lds[73728];
  // XCD-chunked swizzle: 768 blocks = 8 XCDs x 96 (bijective).
  const int flat = blockIdx.x + (blockIdx.y << 1) + (blockIdx.z << 7); // x + 2y + 128z
  const int swz  = (flat & 7) * 96 + (flat >> 3);
  const int colT = swz & 1;
  const int rowT = (swz >> 1) & 63;
  const int z    = swz >> 7;
  const int rowBase = rowT * 256;
  const int colBase = colT * 128;
  f32x4 acc[4][4];
  gemm_tbuf(A.X, A.W[z], rowBase, colBase, lds, acc);

  const int tid  = threadIdx.x;
  const int lane = tid & 63;
  const int wv   = tid >> 6;
  const int wrow = (wv >> 1) * 64;
  const int wcol = (wv & 1) * 64;
  const int m    = lane & 15;
  const int quad = lane >> 4;

  const float* bias = A.bias[z];
  const float bs = A.bscale[z];
  const int f32o = A.isf32[z];
  float* fo = (float*)A.out[z];
  __hip_bfloat16* bo = (__hip_bfloat16*)A.out[z];

  #pragma unroll
  for (int si = 0; si < 4; ++si) {
    const int i = rowBase + wrow + si * 16 + m;
    #pragma unroll
    for (int sj = 0; sj < 4; ++sj) {
      const int j0 = colBase + wcol + sj * 16 + quad * 4;   // 4-aligned
      const f32x4 bj = *(const f32x4*)(bias + j0);          // 16B-aligned
      f32x4 v;
      #pragma unroll
      for (int r = 0; r < 4; ++r) v[r] = acc[si][sj][r] + bj[r] * bs;
      const size_t idx = (size_t)i * DD + j0;
      if (f32o) {
        *(f32x4*)(fo + idx) = v;        // cached: L2 merges into full lines
      } else {
        bf16x4 o;
        o.a = __float2bfloat16(v[0]);
        o.b = __float2bfloat16(v[1]);
        o.c = __float2bfloat16(v[2]);
        o.d = __float2bfloat16(v[3]);
        *(bf16x4*)(bo + idx) = o;       // cached 8B packed store
      }
    }
  }
}

// ---------------- kernel 4: score GEMM + rel gather + mask -----------------
__global__ __launch_bounds__(512, 4) void score_k(const __hip_bfloat16* __restrict__ Q1,
                                                  const __hip_bfloat16* __restrict__ K1,
                                                  const float* __restrict__ QR1,
                                                  const __hip_bfloat16* __restrict__ Q2,
                                                  const __hip_bfloat16* __restrict__ K2,
                                                  const float* __restrict__ QR2,
                                                  const int* __restrict__ mask,
                                                  float* __restrict__ out) {
  __shared__ char lds[73728];
  // XCD-chunked swizzle: 2048 blocks = 8 XCDs x 256 (bijective). Each XCD's
  // chunk covers 2 z-slices; per z, Q+K+QR panels ~= 4 MB ~= one XCD L2.
  // (round-2 evidence: FETCH_SIZE 107 -> 27 MB with this family of mapping)
  const int flat = blockIdx.x + (blockIdx.y << 4) + (blockIdx.z << 7); // 0..2047
  const int swz  = (flat & 7) * 256 + (flat >> 3);
  const int colT = swz & 15;                // 0..15  (N=128 tiles)
  const int rowT = (swz >> 4) & 7;          // 0..7   (M=256 tiles)
  const int z    = swz >> 7;                // h*8 + b
  const int h = z >> 3, b = z & 7;
  const __hip_bfloat16* Q  = (h ? Q2 : Q1) + (size_t)b * SQ * DD;
  const __hip_bfloat16* Kk = (h ? K2 : K1) + (size_t)b * SQ * DD;
  const float* QR = (h ? QR2 : QR1) + (size_t)b * SQ * DD;
  const int* mk = mask + b * SQ;
  float* outp = out + (size_t)z * SQ * SQ;
  const int rowBase = rowT * 256;
  const int colBase = colT * 128;

  f32x4 acc[4][4];
  gemm_tbuf(Q, Kk, rowBase, colBase, lds, acc);

  const int tid  = threadIdx.x;
  const int lane = tid & 63;
  const int wv   = tid >> 6;
  const int wrow = (wv >> 1) * 64;
  const int wcol = (wv & 1) * 64;
  const int m    = lane & 15;
  const int quad = lane >> 4;

  // Block-uniform rel mode for a 256-row x 128-col tile; delta = colBase-rowBase
  // is a multiple of 128. d = j-i spans [delta-255, delta+127].
  // delta >= 384  -> every d >= 65  -> clip to +64 (qr col 128)
  // delta <= -256 -> every d <= -65 -> clip to -64 (qr col 0)
  // else (~23% of tiles): general per-element gather.
  const int delta = colBase - rowBase;
  const int mode = (delta >= 384) ? 1 : (delta <= -256 ? -1 : 0);

  // column masks: one int4 per sj (j0 is 4-aligned)
  int4 mj4[4];
  #pragma unroll
  for (int sj = 0; sj < 4; ++sj)
    mj4[sj] = *(const int4*)(mk + colBase + wcol + sj * 16 + quad * 4);

  #pragma unroll
  for (int si = 0; si < 4; ++si) {
    const int i = rowBase + wrow + si * 16 + m;
    const int mi = mk[i];
    const float* qr_row = QR + (size_t)i * DD;
    float* orow = outp + (size_t)i * SQ;
    float relc = 0.f;
    if (mode) relc = qr_row[mode == 1 ? 2 * KREL : 0];  // one load per row
    #pragma unroll
    for (int sj = 0; sj < 4; ++sj) {
      const int j0 = colBase + wcol + sj * 16 + quad * 4;
      f32x4 v;
      if (mode) {
        #pragma unroll
        for (int r = 0; r < 4; ++r) v[r] = acc[si][sj][r] + relc;
      } else {
        #pragma unroll
        for (int r = 0; r < 4; ++r) {
          int d = j0 + r - i;
          d = d < -KREL ? -KREL : (d > KREL ? KREL : d);
          v[r] = acc[si][sj][r] + qr_row[d + KREL];
        }
      }
      const int4 mj = mj4[sj];
      if (!(mi && mj.x)) v[0] = -1e18f;
      if (!(mi && mj.y)) v[1] = -1e18f;
      if (!(mi && mj.z)) v[2] = -1e18f;
      if (!(mi && mj.w)) v[3] = -1e18f;
      *(f32x4*)(orow + j0) = v;  // cached 16B store: L2 merges into full lines
    }
  }
}

// ---------------- launch ---------------------------------------------------
extern "C" void kernel_launch(void* const* d_in, const int* in_sizes, int n_in,
                              void* d_out, int out_size, void* d_ws, size_t ws_size,
                              hipStream_t stream) {
  const float* repre = (const float*)d_in[0];
  const int*   mask  = (const int*)d_in[1];
  const float* wq1 = (const float*)d_in[2];
  const float* bq1 = (const float*)d_in[3];
  const float* wk1 = (const float*)d_in[4];
  const float* bk1 = (const float*)d_in[5];
  const float* rel1 = (const float*)d_in[6];
  const float* wq2 = (const float*)d_in[7];
  const float* bq2 = (const float*)d_in[8];
  const float* wk2 = (const float*)d_in[9];
  const float* bk2 = (const float*)d_in[10];
  const float* rel2 = (const float*)d_in[11];

  char* ws = (char*)d_ws;
  __hip_bfloat16* xbf   = (__hip_bfloat16*)(ws + OFF_XBF);
  __hip_bfloat16* wbf   = (__hip_bfloat16*)(ws + OFF_WBF);
  __hip_bfloat16* relbf = (__hip_bfloat16*)(ws + OFF_RELBF);
  __hip_bfloat16* wr    = (__hip_bfloat16*)(ws + OFF_WR);
  float*          cr    = (float*)(ws + OFF_CR);
  __hip_bfloat16* Q1 = (__hip_bfloat16*)(ws + OFF_QK);
  __hip_bfloat16* K1 = Q1 + (size_t)16384 * 256;
  __hip_bfloat16* Q2 = K1 + (size_t)16384 * 256;
  __hip_bfloat16* K2 = Q2 + (size_t)16384 * 256;
  float* QR1 = (float*)(ws + OFF_QR);
  float* QR2 = QR1 + (size_t)16384 * 256;

  // 1. convert f32 -> bf16 (scale 1/16 folded into wq)
  ConvArgs ca;
  ca.src[0] = repre; ca.dst[0] = xbf;            ca.scale[0] = 1.f;
  ca.src[1] = wq1;   ca.dst[1] = wbf;            ca.scale[1] = 0.0625f;
  ca.src[2] = wk1;   ca.dst[2] = wbf + 65536;    ca.scale[2] = 1.f;
  ca.src[3] = wq2;   ca.dst[3] = wbf + 131072;   ca.scale[3] = 0.0625f;
  ca.src[4] = wk2;   ca.dst[4] = wbf + 196608;   ca.scale[4] = 1.f;
  ca.src[5] = rel1;  ca.dst[5] = relbf;          ca.scale[5] = 1.f;
  ca.src[6] = rel2;  ca.dst[6] = relbf + 33024;  ca.scale[6] = 1.f;
  const int sizes[7] = {4194304, 65536, 65536, 65536, 65536, 33024, 33024};
  int cum = 0;
  ca.cum4[0] = 0;
  for (int i = 0; i < 7; ++i) { cum += sizes[i] / 4; ca.cum4[i + 1] = cum; }
  const int nblk = (cum + 255) / 256;
  hipLaunchKernelGGL(convert_k, dim3(nblk), dim3(256), 0, stream, ca);

  // 2. Wr = rel @ (wq/16), cr = rel @ (bq/16)
  hipLaunchKernelGGL(wr_k, dim3(256, 2), dim3(256), 0, stream, relbf, wbf, bq1, bq2, wr, cr);

  // 3. projections: q1,k1,qr1,q2,k2,qr2  (256x128 tiles, 512 threads)
  QKArgs qa;
  qa.X = xbf;
  qa.W[0] = wbf;          qa.bias[0] = bq1;      qa.bscale[0] = 0.0625f; qa.out[0] = Q1;  qa.isf32[0] = 0;
  qa.W[1] = wbf + 65536;  qa.bias[1] = bk1;      qa.bscale[1] = 1.f;     qa.out[1] = K1;  qa.isf32[1] = 0;
  qa.W[2] = wr;           qa.bias[2] = cr;       qa.bscale[2] = 1.f;     qa.out[2] = QR1; qa.isf32[2] = 1;
  qa.W[3] = wbf + 131072; qa.bias[3] = bq2;      qa.bscale[3] = 0.0625f; qa.out[3] = Q2;  qa.isf32[3] = 0;
  qa.W[4] = wbf + 196608; qa.bias[4] = bk2;      qa.bscale[4] = 1.f;     qa.out[4] = K2;  qa.isf32[4] = 0;
  qa.W[5] = wr + 65536;   qa.bias[5] = cr + 256; qa.bscale[5] = 1.f;     qa.out[5] = QR2; qa.isf32[5] = 1;
  hipLaunchKernelGGL(qk_k, dim3(2, 64, 6), dim3(512), 0, stream, qa);

  // 4. scores = Q@K^T + gather(QR) + mask  -> d_out [2,8,2048,2048] f32
  hipLaunchKernelGGL(score_k, dim3(16, 8, 16), dim3(512), 0, stream,
                     Q1, K1, QR1, Q2, K2, QR2, mask, (float*)d_out);
}

// Round 7
// 404.728 us; speedup vs baseline: 1.0294x; 1.0294x over previous
//
#include <hip/hip_runtime.h>
#include <hip/hip_bf16.h>

typedef __attribute__((ext_vector_type(4))) float f32x4;
typedef __attribute__((ext_vector_type(8))) short short8;

struct bf16x4 { __hip_bfloat16 a, b, c, d; };  // 8-byte packed store unit

#define BS   8
#define SQ   2048
#define DD   256
#define KREL 64
#define NREL 129  // 2*KREL+1

// ---------------- workspace layout (bytes) ----------------
static const size_t OFF_XBF   = 0;          // bf16 [16384,256] x
static const size_t OFF_WBF   = 8388608;    // bf16 4x[256,256]: wq1/16, wk1, wq2/16, wk2
static const size_t OFF_RELBF = 8912896;    // bf16 2x[129,256]
static const size_t OFF_WR    = 9044992;    // bf16 2x[256,256] Wr = rel @ (wq/16), rows>=129 zero
static const size_t OFF_CR    = 9307136;    // f32  2x[256]     cr = rel @ (bq/16), rows>=129 zero
static const size_t OFF_QK    = 9309184;    // bf16 4x[16384,256]: Q1,K1,Q2,K2
static const size_t OFF_QR    = 42863616;   // f32  2x[16384,256]: QR1,QR2 (cols>=129 zero)

// ---------------- kernel 1: f32 -> bf16 convert (with scale fold) ----------
struct ConvArgs {
  const float* src[7];
  __hip_bfloat16* dst[7];
  float scale[7];
  int cum4[8];
};
struct bf4 { __hip_bfloat16 a, b, c, d; };

__global__ __launch_bounds__(256) void convert_k(ConvArgs A) {
  const int idx = blockIdx.x * 256 + threadIdx.x;
  if (idx >= A.cum4[7]) return;
  int rg = 0;
  #pragma unroll
  for (int t = 1; t < 7; ++t) rg += (idx >= A.cum4[t]);
  const int local = idx - A.cum4[rg];
  const float4 v = ((const float4*)A.src[rg])[local];
  const float sc = A.scale[rg];
  bf4 o;
  o.a = __float2bfloat16(v.x * sc);
  o.b = __float2bfloat16(v.y * sc);
  o.c = __float2bfloat16(v.z * sc);
  o.d = __float2bfloat16(v.w * sc);
  ((bf4*)A.dst[rg])[local] = o;  // cached: xbf is read immediately by qk_k
}

// ---------------- kernel 2: Wr[h] = rel_bf[h] @ wq_bf[h], cr[h] = rel @ bq/16
__global__ __launch_bounds__(256) void wr_k(const __hip_bfloat16* __restrict__ relbf,
                                            const __hip_bfloat16* __restrict__ wbf,
                                            const float* __restrict__ bq1,
                                            const float* __restrict__ bq2,
                                            __hip_bfloat16* __restrict__ wr,
                                            float* __restrict__ cr) {
  const int r = blockIdx.x;   // 0..255 (rows >=129 -> zero)
  const int h = blockIdx.y;   // 0..1
  const int e = threadIdx.x;  // 0..255
  const int lane = e & 63, wv = e >> 6;
  const __hip_bfloat16* rel = relbf + (size_t)h * (NREL * DD);
  const __hip_bfloat16* wq  = wbf + (size_t)h * (2 * DD * DD);  // wq1s at 0, wq2s at 131072
  float a0 = 0.f, a1 = 0.f, a2 = 0.f, a3 = 0.f;
  if (r < NREL) {
    #pragma unroll 4
    for (int d = 0; d < DD; d += 4) {
      // rel row loads are thread-uniform -> scalar; wq loads coalesced (512B/row)
      a0 += __bfloat162float(rel[r * DD + d + 0]) * __bfloat162float(wq[(d + 0) * DD + e]);
      a1 += __bfloat162float(rel[r * DD + d + 1]) * __bfloat162float(wq[(d + 1) * DD + e]);
      a2 += __bfloat162float(rel[r * DD + d + 2]) * __bfloat162float(wq[(d + 2) * DD + e]);
      a3 += __bfloat162float(rel[r * DD + d + 3]) * __bfloat162float(wq[(d + 3) * DD + e]);
    }
  }
  wr[((size_t)h * DD + r) * DD + e] = __float2bfloat16((a0 + a1) + (a2 + a3));

  // cr[h,r] = sum_e bq[e]/16 * rel[r,e]  -- parallel block reduction
  const float* bq = h ? bq2 : bq1;
  float p = (r < NREL) ? bq[e] * 0.0625f * __bfloat162float(rel[r * DD + e]) : 0.f;
  #pragma unroll
  for (int o = 32; o > 0; o >>= 1) p += __shfl_down(p, o, 64);
  __shared__ float wred[4];
  if (lane == 0) wred[wv] = p;
  __syncthreads();
  if (e == 0) cr[h * DD + r] = (wred[0] + wred[1]) + (wred[2] + wred[3]);
}

// ---------------- triple-buffered 128x128 NT-GEMM core (round-4 template) --
// C[i,j] = sum_d A[i,d] * B[j,d]; A,B row-major bf16, ld=256, K=256.
// 256 threads = 4 waves in 2x2; each wave does 64x64 via 4x4 MFMA 16x16x32.
// MFMA operands are SWAPPED (mfma(bf, af)): lane holds 4 consecutive j.
//
// T2 LDS chunk-swizzle (round-6; resubmitted round-7 after infra flake).
// The unswizzled fragment read addr = row*64 + quad*16 (row stride 64B =
// 16 banks) put 8 lanes on each bank (8-way conflict, ~2.9x; measured
// 4.19M SQ_LDS_BANK_CONFLICT). Swizzle chunks within each 64B row:
//   c' = c ^ ((row>>1)&3)
// Per rule #21 (global_load_lds writes linearly): keep LDS dest linear,
// PRE-SWIZZLE the global source (lane owning chunk (r,c') fetches global
// chunk c'^((r>>1)&3)), and swizzle the read (quad ^ ((m>>1)&3), constant
// per lane). 16 lanes/quad now spread over 8 bank positions = 2-way = free.
// Audit: involution matches both sides ((R>>1)&3 == (m>>1)&3 since wrow,
// s*16 don't touch bits 1-2); max global index k0+kk+8 = 256 = DD, in
// bounds; control flow identical to the round-4 PASSING kernel.
__device__ __forceinline__ void stage_tile(const __hip_bfloat16* __restrict__ A,
                                           const __hip_bfloat16* __restrict__ B,
                                           int rowBase, int colBase, int k0,
                                           char* As, char* Bs, int wv, int lane) {
  #pragma unroll
  for (int inst = 0; inst < 2; ++inst) {
    const int lds_off = wv * 2048 + inst * 1024;       // wave-uniform byte offset
    const int chunk = (lds_off >> 4) + lane;           // this lane's 16B chunk
    const int r  = chunk >> 2;                         // tile row 0..127
    const int c  = chunk & 3;                          // chunk-in-row (LDS position)
    const int kk = (c ^ ((r >> 1) & 3)) * 8;           // pre-swizzled global chunk
    __builtin_amdgcn_global_load_lds(
        (const __attribute__((address_space(1))) void*)(A + (size_t)(rowBase + r) * DD + k0 + kk),
        (__attribute__((address_space(3))) void*)(As + lds_off), 16, 0, 0);
    __builtin_amdgcn_global_load_lds(
        (const __attribute__((address_space(1))) void*)(B + (size_t)(colBase + r) * DD + k0 + kk),
        (__attribute__((address_space(3))) void*)(Bs + lds_off), 16, 0, 0);
  }
}

__device__ __forceinline__ void gemm_tbuf(const __hip_bfloat16* __restrict__ A,
                                          const __hip_bfloat16* __restrict__ B,
                                          int rowBase, int colBase,
                                          char* lds,  // 48 KB: 3 x (As 8KB + Bs 8KB)
                                          f32x4 acc[4][4]) {
  const int tid  = threadIdx.x;
  const int lane = tid & 63;
  const int wv   = tid >> 6;
  const int wrow = (wv >> 1) * 64;
  const int wcol = (wv & 1) * 64;
  const int m    = lane & 15;
  const int quad = lane >> 4;
  // swizzled read chunk offset: rows are base16+m -> selector is (m>>1)&3
  const int qs   = (quad ^ ((m >> 1) & 3)) * 16;

  char* As[3] = {lds,        lds + 16384, lds + 32768};
  char* Bs[3] = {lds + 8192, lds + 24576, lds + 40960};

  const f32x4 zf = {0.f, 0.f, 0.f, 0.f};
  #pragma unroll
  for (int si = 0; si < 4; ++si)
    #pragma unroll
    for (int sj = 0; sj < 4; ++sj) acc[si][sj] = zf;

  // prologue: two stages in flight (8 loads/wave)
  stage_tile(A, B, rowBase, colBase, 0,  As[0], Bs[0], wv, lane);
  stage_tile(A, B, rowBase, colBase, 32, As[1], Bs[1], wv, lane);

  #pragma unroll
  for (int k = 0; k < 8; ++k) {
    // retire stage k (leave stage k+1 in flight); k=7 has nothing newer
    if (k < 7) asm volatile("s_waitcnt vmcnt(4)" ::: "memory");
    else       asm volatile("s_waitcnt vmcnt(0)" ::: "memory");
    __builtin_amdgcn_sched_barrier(0);       // pin: nothing slides into the counted window
    __builtin_amdgcn_s_barrier();            // all waves' stage k landed
    __builtin_amdgcn_sched_barrier(0);       // pin: no ds_read hoisted above barrier
    if (k < 6)
      stage_tile(A, B, rowBase, colBase, (k + 2) * 32,
                 As[(k + 2) % 3], Bs[(k + 2) % 3], wv, lane);

    const int cur = k % 3;
    short8 af[4], bf[4];
    #pragma unroll
    for (int s = 0; s < 4; ++s) {
      af[s] = *(const short8*)(As[cur] + (wrow + s * 16 + m) * 64 + qs);
      bf[s] = *(const short8*)(Bs[cur] + (wcol + s * 16 + m) * 64 + qs);
    }
    // swapped operands: D^T tile -> lane holds 4 consecutive j per acc
    #pragma unroll
    for (int si = 0; si < 4; ++si)
      #pragma unroll
      for (int sj = 0; sj < 4; ++sj)
        acc[si][sj] = __builtin_amdgcn_mfma_f32_16x16x32_bf16(bf[sj], af[si], acc[si][sj], 0, 0, 0);
  }
}

// ---------------- kernel 3: unified projection GEMM (q1,k1,qr1,q2,k2,qr2) --
struct QKArgs {
  const __hip_bfloat16* X;      // [16384,256]
  const __hip_bfloat16* W[6];   // each [256,256] (N x K, row-major)
  const float* bias[6];
  void* out[6];
  float bscale[6];
  int isf32[6];
};

__global__ __launch_bounds__(256) void qk_k(QKArgs A) {
  __shared__ char lds[49152];
  // XCD-chunked swizzle: 1536 blocks = 8 XCDs x 192 (bijective).
  const int flat = blockIdx.x + (blockIdx.y << 1) + (blockIdx.z << 8); // x + 2y + 256z
  const int swz  = (flat & 7) * 192 + (flat >> 3);
  const int colT = swz & 1;
  const int rowT = (swz >> 1) & 127;
  const int z    = swz >> 8;
  const int rowBase = rowT * 128;
  const int colBase = colT * 128;
  f32x4 acc[4][4];
  gemm_tbuf(A.X, A.W[z], rowBase, colBase, lds, acc);

  const int tid  = threadIdx.x;
  const int lane = tid & 63;
  const int wv   = tid >> 6;
  const int wrow = (wv >> 1) * 64;
  const int wcol = (wv & 1) * 64;
  const int m    = lane & 15;
  const int quad = lane >> 4;

  const float* bias = A.bias[z];
  const float bs = A.bscale[z];
  const int f32o = A.isf32[z];
  float* fo = (float*)A.out[z];
  __hip_bfloat16* bo = (__hip_bfloat16*)A.out[z];

  #pragma unroll
  for (int si = 0; si < 4; ++si) {
    const int i = rowBase + wrow + si * 16 + m;
    #pragma unroll
    for (int sj = 0; sj < 4; ++sj) {
      const int j0 = colBase + wcol + sj * 16 + quad * 4;   // 4-aligned
      const f32x4 bj = *(const f32x4*)(bias + j0);          // 16B-aligned
      f32x4 v;
      #pragma unroll
      for (int r = 0; r < 4; ++r) v[r] = acc[si][sj][r] + bj[r] * bs;
      const size_t idx = (size_t)i * DD + j0;
      if (f32o) {
        *(f32x4*)(fo + idx) = v;        // cached: L2 merges into full lines
      } else {
        bf16x4 o;
        o.a = __float2bfloat16(v[0]);
        o.b = __float2bfloat16(v[1]);
        o.c = __float2bfloat16(v[2]);
        o.d = __float2bfloat16(v[3]);
        *(bf16x4*)(bo + idx) = o;       // cached 8B packed store
      }
    }
  }
}

// ---------------- kernel 4: score GEMM + rel gather + mask -----------------
__global__ __launch_bounds__(256) void score_k(const __hip_bfloat16* __restrict__ Q1,
                                               const __hip_bfloat16* __restrict__ K1,
                                               const float* __restrict__ QR1,
                                               const __hip_bfloat16* __restrict__ Q2,
                                               const __hip_bfloat16* __restrict__ K2,
                                               const float* __restrict__ QR2,
                                               const int* __restrict__ mask,
                                               float* __restrict__ out) {
  __shared__ char lds[49152];
  // XCD-chunked swizzle: 4096 blocks = 8 XCDs x 512 (bijective). Each XCD's
  // chunk covers 2 z-slices; per z, Q+K+QR panels = 4 MB ~= one XCD L2.
  // (round-2 evidence: FETCH_SIZE 107 -> 27 MB with this mapping)
  const int flat = blockIdx.x + (blockIdx.y << 4) + (blockIdx.z << 8); // 0..4095
  const int swz  = ((flat & 7) << 9) | (flat >> 3);
  const int colT = swz & 15;
  const int rowT = (swz >> 4) & 15;
  const int z    = swz >> 8;                // h*8 + b
  const int h = z >> 3, b = z & 7;
  const __hip_bfloat16* Q  = (h ? Q2 : Q1) + (size_t)b * SQ * DD;
  const __hip_bfloat16* Kk = (h ? K2 : K1) + (size_t)b * SQ * DD;
  const float* QR = (h ? QR2 : QR1) + (size_t)b * SQ * DD;
  const int* mk = mask + b * SQ;
  float* outp = out + (size_t)z * SQ * SQ;
  const int rowBase = rowT * 128;
  const int colBase = colT * 128;

  f32x4 acc[4][4];
  gemm_tbuf(Q, Kk, rowBase, colBase, lds, acc);

  const int tid  = threadIdx.x;
  const int lane = tid & 63;
  const int wv   = tid >> 6;
  const int wrow = (wv >> 1) * 64;
  const int wcol = (wv & 1) * 64;
  const int m    = lane & 15;
  const int quad = lane >> 4;

  // Block-uniform rel mode: tile diag offsets are multiples of 128.
  // delta >= 192  -> every d=j-i >= 65  -> clip to +64 (qr col 128)
  // delta <= -192 -> every d <= -65     -> clip to -64 (qr col 0)
  // else (3 tile-diagonals, ~18% of tiles): general per-element gather.
  const int delta = colBase - rowBase;
  const int mode = (delta >= 192) ? 1 : (delta <= -192 ? -1 : 0);

  // column masks: one int4 per sj (j0 is 4-aligned)
  int4 mj4[4];
  #pragma unroll
  for (int sj = 0; sj < 4; ++sj)
    mj4[sj] = *(const int4*)(mk + colBase + wcol + sj * 16 + quad * 4);

  #pragma unroll
  for (int si = 0; si < 4; ++si) {
    const int i = rowBase + wrow + si * 16 + m;
    const int mi = mk[i];
    const float* qr_row = QR + (size_t)i * DD;
    float* orow = outp + (size_t)i * SQ;
    float relc = 0.f;
    if (mode) relc = qr_row[mode == 1 ? 2 * KREL : 0];  // one load per row
    #pragma unroll
    for (int sj = 0; sj < 4; ++sj) {
      const int j0 = colBase + wcol + sj * 16 + quad * 4;
      f32x4 v;
      if (mode) {
        #pragma unroll
        for (int r = 0; r < 4; ++r) v[r] = acc[si][sj][r] + relc;
      } else {
        #pragma unroll
        for (int r = 0; r < 4; ++r) {
          int d = j0 + r - i;
          d = d < -KREL ? -KREL : (d > KREL ? KREL : d);
          v[r] = acc[si][sj][r] + qr_row[d + KREL];
        }
      }
      const int4 mj = mj4[sj];
      if (!(mi && mj.x)) v[0] = -1e18f;
      if (!(mi && mj.y)) v[1] = -1e18f;
      if (!(mi && mj.z)) v[2] = -1e18f;
      if (!(mi && mj.w)) v[3] = -1e18f;
      *(f32x4*)(orow + j0) = v;  // cached 16B store: L2 merges into full lines
    }
  }
}

// ---------------- launch ---------------------------------------------------
extern "C" void kernel_launch(void* const* d_in, const int* in_sizes, int n_in,
                              void* d_out, int out_size, void* d_ws, size_t ws_size,
                              hipStream_t stream) {
  const float* repre = (const float*)d_in[0];
  const int*   mask  = (const int*)d_in[1];
  const float* wq1 = (const float*)d_in[2];
  const float* bq1 = (const float*)d_in[3];
  const float* wk1 = (const float*)d_in[4];
  const float* bk1 = (const float*)d_in[5];
  const float* rel1 = (const float*)d_in[6];
  const float* wq2 = (const float*)d_in[7];
  const float* bq2 = (const float*)d_in[8];
  const float* wk2 = (const float*)d_in[9];
  const float* bk2 = (const float*)d_in[10];
  const float* rel2 = (const float*)d_in[11];

  char* ws = (char*)d_ws;
  __hip_bfloat16* xbf   = (__hip_bfloat16*)(ws + OFF_XBF);
  __hip_bfloat16* wbf   = (__hip_bfloat16*)(ws + OFF_WBF);
  __hip_bfloat16* relbf = (__hip_bfloat16*)(ws + OFF_RELBF);
  __hip_bfloat16* wr    = (__hip_bfloat16*)(ws + OFF_WR);
  float*          cr    = (float*)(ws + OFF_CR);
  __hip_bfloat16* Q1 = (__hip_bfloat16*)(ws + OFF_QK);
  __hip_bfloat16* K1 = Q1 + (size_t)16384 * 256;
  __hip_bfloat16* Q2 = K1 + (size_t)16384 * 256;
  __hip_bfloat16* K2 = Q2 + (size_t)16384 * 256;
  float* QR1 = (float*)(ws + OFF_QR);
  float* QR2 = QR1 + (size_t)16384 * 256;

  // 1. convert f32 -> bf16 (scale 1/16 folded into wq)
  ConvArgs ca;
  ca.src[0] = repre; ca.dst[0] = xbf;            ca.scale[0] = 1.f;
  ca.src[1] = wq1;   ca.dst[1] = wbf;            ca.scale[1] = 0.0625f;
  ca.src[2] = wk1;   ca.dst[2] = wbf + 65536;    ca.scale[2] = 1.f;
  ca.src[3] = wq2;   ca.dst[3] = wbf + 131072;   ca.scale[3] = 0.0625f;
  ca.src[4] = wk2;   ca.dst[4] = wbf + 196608;   ca.scale[4] = 1.f;
  ca.src[5] = rel1;  ca.dst[5] = relbf;          ca.scale[5] = 1.f;
  ca.src[6] = rel2;  ca.dst[6] = relbf + 33024;  ca.scale[6] = 1.f;
  const int sizes[7] = {4194304, 65536, 65536, 65536, 65536, 33024, 33024};
  int cum = 0;
  ca.cum4[0] = 0;
  for (int i = 0; i < 7; ++i) { cum += sizes[i] / 4; ca.cum4[i + 1] = cum; }
  const int nblk = (cum + 255) / 256;
  hipLaunchKernelGGL(convert_k, dim3(nblk), dim3(256), 0, stream, ca);

  // 2. Wr = rel @ (wq/16), cr = rel @ (bq/16)
  hipLaunchKernelGGL(wr_k, dim3(256, 2), dim3(256), 0, stream, relbf, wbf, bq1, bq2, wr, cr);

  // 3. projections: q1,k1,qr1,q2,k2,qr2
  QKArgs qa;
  qa.X = xbf;
  qa.W[0] = wbf;          qa.bias[0] = bq1;      qa.bscale[0] = 0.0625f; qa.out[0] = Q1;  qa.isf32[0] = 0;
  qa.W[1] = wbf + 65536;  qa.bias[1] = bk1;      qa.bscale[1] = 1.f;     qa.out[1] = K1;  qa.isf32[1] = 0;
  qa.W[2] = wr;           qa.bias[2] = cr;       qa.bscale[2] = 1.f;     qa.out[2] = QR1; qa.isf32[2] = 1;
  qa.W[3] = wbf + 131072; qa.bias[3] = bq2;      qa.bscale[3] = 0.0625f; qa.out[3] = Q2;  qa.isf32[3] = 0;
  qa.W[4] = wbf + 196608; qa.bias[4] = bk2;      qa.bscale[4] = 1.f;     qa.out[4] = K2;  qa.isf32[4] = 0;
  qa.W[5] = wr + 65536;   qa.bias[5] = cr + 256; qa.bscale[5] = 1.f;     qa.out[5] = QR2; qa.isf32[5] = 1;
  hipLaunchKernelGGL(qk_k, dim3(2, 128, 6), dim3(256), 0, stream, qa);

  // 4. scores = Q@K^T + gather(QR) + mask  -> d_out [2,8,2048,2048] f32
  hipLaunchKernelGGL(score_k, dim3(16, 16, 16), dim3(256), 0, stream,
                     Q1, K1, QR1, Q2, K2, QR2, mask, (float*)d_out);
}